// Round 15
// baseline (483.484 us; speedup 1.0000x reference)
//
#include <hip/hip_runtime.h>

// DILATE loss via the soft-DTW forward/backward identity:
//   E[i,j] = exp((V - R[i,j] - Rrev[i,j] + D[i,j]) / gamma)
// Round 15: BOTH direction passes fused into ONE WAVE's instruction stream
// (each lane carries dir0 + dir1 recurrence state; 4 cells/step from two
// independent chains -> chain-latency bubbles filled by true ILP, not
// co-residency). One block per sample, 4 waves, r14's branch-free skewed
// stores kept. Scaled domain R'' = R * (100/ln2).

#define NSEQ 512
#define K2   144.269504088896f      // (1/gamma)*log2(e) = 100/ln2
#define SC   0.006931471805599453f  // ln2/100
#define BIGV 1e10f
#define ALPHA 0.5f
#define PACKS 327680                // floats per sample per dir (4*640*128)

// full-wave shift toward higher lanes by 1 (lane l gets lane l-1); lane 0 -> BIGV
__device__ __forceinline__ float shr1(float v) {
    return __int_as_float(__builtin_amdgcn_update_dpp(
        __float_as_int(BIGV), __float_as_int(v), 0x138 /*wave_shr:1*/,
        0xF, 0xF, false));
}

__device__ __forceinline__ float sm_cell(float a, float b, float c,
                                         float tv, float ov) {
    const float mn = fminf(fminf(a, b), c);
    const float mx = fmaxf(fmaxf(a, b), c);
    const float md = __builtin_amdgcn_fmed3f(a, b, c);
    const float s = 1.f + __builtin_exp2f(mn - md) + __builtin_exp2f(mn - mx);
    const float dv = tv - ov;
    return fmaf(dv * dv, K2, mn - __builtin_log2f(s));
}

__global__ __launch_bounds__(256) void sdtw_pass(
    const float* __restrict__ outp, const float* __restrict__ targ,
    float* __restrict__ slabA, float* __restrict__ slabB,
    float* __restrict__ vals, float* __restrict__ vraw, int kbase)
{
    const int tid = threadIdx.x;
    const int w = tid >> 6, l = tid & 63;
    const int i0 = 128 * w + 2 * l;          // lane owns rows i0, i0+1 (both dirs)
    const int kk = blockIdx.x;
    const int k  = kbase + kk;
    const bool lane0 = (l == 0), lane63 = (l == 63);

    __shared__ float o_pad[2][644];   // o[j] at [j+1], pads 0   (dir 1 reversed)
    __shared__ float t_sh[2][516];
    __shared__ float Rbf[2][3][644];  // boundary row 128(w+1)-1: col c at [c+1]
    __shared__ float dummyF[644];     // virtual row -1: [0]=0 (R[-1,-1]), else BIG

    for (int q = tid; q < 644; q += 256) {
        o_pad[0][q] = 0.f; o_pad[1][q] = 0.f; dummyF[q] = BIGV;
    }
    for (int q = tid; q < 516; q += 256) { t_sh[0][q] = 0.f; t_sh[1][q] = 0.f; }
    __syncthreads();
    if (tid == 0) {
        dummyF[0] = 0.f;                     // virtual R[-1,-1] = 0
        Rbf[0][0][0] = BIGV; Rbf[0][1][0] = BIGV; Rbf[0][2][0] = BIGV;
        Rbf[1][0][0] = BIGV; Rbf[1][1][0] = BIGV; Rbf[1][2][0] = BIGV;
    }
    for (int q = tid; q < NSEQ; q += 256) {
        const float ov = outp[(size_t)k * NSEQ + q];
        const float tv = targ[(size_t)k * NSEQ + q];
        o_pad[0][1 + q] = ov;  o_pad[1][1 + (NSEQ - 1 - q)] = ov;
        t_sh[0][q]      = tv;  t_sh[1][NSEQ - 1 - q]        = tv;
    }
    __syncthreads();

    const float t0a = t_sh[0][i0], t1a = t_sh[0][i0 + 1];
    const float t0b = t_sh[1][i0], t1b = t_sh[1][i0 + 1];
    const float* RbfRa = (w == 0) ? dummyF : Rbf[0][w - 1];
    const float* RbfRb = (w == 0) ? dummyF : Rbf[1][w - 1];
    float* RbfWa = Rbf[0][w < 3 ? w : 2];
    float* RbfWb = Rbf[1][w < 3 ? w : 2];

    float2* __restrict__ spA2 =
        (float2*)(slabA + (size_t)kk * PACKS) + w * 40960 + l;
    float2* __restrict__ spB2 =
        (float2*)(slabB + (size_t)kk * PACKS) + w * 40960 + l;

    // dir0 state (suffix A) / dir1 state (suffix B)
    float A10 = BIGV, A11 = BIGV, A20 = BIGV, A21 = BIGV, sbvA = BIGV;
    float B10 = BIGV, B11 = BIGV, B20 = BIGV, B21 = BIGV, sbvB = BIGV;
    float rfinal = BIGV;

    for (int ss = 0; ss < 19; ++ss) {
        const int mw = ss - 3 * w;               // wave-local window
        if (0 <= mw && mw < 10) {
            const int tb = (mw + 2 * w) * 64;    // global diag base
            int j0 = tb - i0;
            #pragma unroll 8
            for (int u = 0; u < 64; ++u, ++j0) {
                const int ob = (j0 > 0) ? j0 : 0;
                // LDS feeds (independent of both chains)
                const float ojA  = o_pad[0][ob + 1];
                const float ojmA = o_pad[0][ob];
                const float ojB  = o_pad[1][ob + 1];
                const float ojmB = o_pad[1][ob];
                const float bdAa = RbfRa[ob + 1], bdBa = RbfRa[ob];
                const float bdAb = RbfRb[ob + 1], bdBb = RbfRb[ob];
                // cross-lane (DPP, VALU-class)
                const float sAa = shr1(A11);
                const float sAb = shr1(B11);
                const float a0A = lane0 ? bdAa : sAa;
                const float b0A = lane0 ? bdBa : sbvA;
                const float a0B = lane0 ? bdAb : sAb;
                const float b0B = lane0 ? bdBb : sbvB;
                // 4 cells: two independent chains interleave in-issue
                const float r0vA = sm_cell(a0A, b0A, A10, t0a, ojA);
                const float r0vB = sm_cell(a0B, b0B, B10, t0b, ojB);
                const float r1vA = sm_cell(A10, A20, A11, t1a, ojmA);
                const float r1vB = sm_cell(B10, B20, B11, t1b, ojmB);
                const bool act0 = ((unsigned)j0 < 512u);
                const bool act1 = ((unsigned)(j0 - 1) < 512u);
                const float r0nA = act0 ? r0vA : BIGV;
                const float r1nA = act1 ? r1vA : BIGV;
                const float r0nB = act0 ? r0vB : BIGV;
                const float r1nB = act1 ? r1vB : BIGV;
                A20 = A10; A10 = r0nA; A21 = A11; A11 = r1nA; sbvA = sAa;
                B20 = B10; B10 = r0nB; B21 = B11; B11 = r1nB; sbvB = sAb;
                // branch-free skewed stores (garbage lands in never-read slots)
                spA2[0] = make_float2(r0vA, r1vA); spA2 += 64;
                spB2[0] = make_float2(r0vB, r1vB); spB2 += 64;
                if (lane63 && w < 3 && act1) { RbfWa[j0] = r1nA; RbfWb[j0] = r1nB; }
                if (u == 62 && mw == 9) rfinal = r1vA;          // cell (511,511), dir0
            }
        }
        asm volatile("s_waitcnt lgkmcnt(0)\n\ts_barrier" ::: "memory");
    }
    if (w == 3 && lane63) { vals[k] = rfinal * SC; vraw[k] = rfinal; }
}

// ---------------- pointwise E map-reduce ----------------
// E[i,j] = exp2(Vraw - A[i,j] - B[i',j'] + D[i,j]*K2); acc += E*(i-j)^2,
// with (i',j') = (511-i, 511-j) in the reverse pass's skewed layout.
// float offset of cell (i,j): (i>>7)*65536 + (i+j)*128 + (i&127).
__global__ __launch_bounds__(256) void ereduce(
    const float* __restrict__ outp, const float* __restrict__ targ,
    const float* __restrict__ slabA, const float* __restrict__ slabB,
    const float* __restrict__ vraw, float* __restrict__ spart, int kbase)
{
    const int tid = threadIdx.x;
    const int sect = blockIdx.x & 15;
    const int kk = blockIdx.x >> 4;
    const int k = kbase + kk;

    __shared__ float t_sh[NSEQ], o_sh[NSEQ];
    __shared__ float red[4];
    for (int q = tid; q < NSEQ; q += 256) {
        t_sh[q] = targ[(size_t)k * NSEQ + q];
        o_sh[q] = outp[(size_t)k * NSEQ + q];
    }
    __syncthreads();

    const float* __restrict__ A  = slabA + (size_t)kk * PACKS;
    const float* __restrict__ Bs = slabB + (size_t)kk * PACKS;
    const float V = vraw[k];
    float acc = 0.f;
    const int dend = (sect == 15) ? 1023 : (sect * 64 + 64);
    for (int d = sect * 64; d < dend; ++d) {
        const int ilo = (d > 511) ? (d - 511) : 0;
        const int ihi = (d < 512) ? d : 511;
        const int dbA = d * 128;
        const int dbB = (1022 - d) * 128;
        for (int i = ilo + tid; i <= ihi; i += 256) {
            const int i2 = 511 - i;
            const float a = A [((i  >> 7) << 16) + dbA + (i  & 127)];
            const float b = Bs[((i2 >> 7) << 16) + dbB + (i2 & 127)];
            const float dv = t_sh[i] - o_sh[d - i];
            const float arg = fmaf(dv * dv, K2, V - a - b);
            const float E = __builtin_exp2f(arg);       // in [0, 1+eps]
            const float df = (float)(2 * i - d);        // i - j
            acc = fmaf(E * df, df, acc);
        }
    }
    for (int off = 32; off; off >>= 1) acc += __shfl_down(acc, off);
    if ((tid & 63) == 0) red[tid >> 6] = acc;
    __syncthreads();
    if (tid == 0) spart[k * 16 + sect] = red[0] + red[1] + red[2] + red[3];
}

__global__ void finalize_kernel(const float* __restrict__ vals,
                                const float* __restrict__ spart,
                                float* __restrict__ out, int B) {
    int t = threadIdx.x;    // 64 threads
    float v = 0.0f, s = 0.0f;
    for (int q = t; q < B; q += 64) v += vals[q];
    for (int q = t; q < 16 * B; q += 64) s += spart[q];
    for (int off = 32; off; off >>= 1) { v += __shfl_down(v, off); s += __shfl_down(s, off); }
    if (t == 0) {
        float loss_shape = v / (float)B;
        float loss_temporal = (s / (float)B) / ((float)NSEQ * (float)NSEQ);
        out[0] = ALPHA * loss_shape + (1.0f - ALPHA) * loss_temporal;
    }
}

extern "C" void kernel_launch(void* const* d_in, const int* in_sizes, int n_in,
                              void* d_out, int out_size, void* d_ws, size_t ws_size,
                              hipStream_t stream) {
    const float* outputs = (const float*)d_in[0];
    const float* targets = (const float*)d_in[1];
    const int B = in_sizes[0] / NSEQ;    // 64

    // ws: [0,256B) vals, [256,512B) vraw, [512,4608B) spart, [8192, ...) slabs
    float* vals  = (float*)d_ws;
    float* vraw  = vals + 64;
    float* spart = vals + 128;
    float* slabs = (float*)((char*)d_ws + 8192);

    const size_t per_sample = 2 * (size_t)PACKS * sizeof(float);   // 2.5 MiB (A+B)
    size_t avail = (ws_size > 8192) ? (ws_size - 8192) / per_sample : 0;
    int G = (int)((avail < (size_t)B) ? avail : (size_t)B);
    if (G < 1) G = 1;
    float* slabA = slabs;
    float* slabB = slabs + (size_t)G * PACKS;

    for (int kb = 0; kb < B; kb += G) {
        int g = (B - kb < G) ? (B - kb) : G;
        sdtw_pass<<<dim3(g), dim3(256), 0, stream>>>(
            outputs, targets, slabA, slabB, vals, vraw, kb);
        ereduce<<<dim3(16 * g), dim3(256), 0, stream>>>(
            outputs, targets, slabA, slabB, vraw, spart, kb);
    }
    finalize_kernel<<<dim3(1), dim3(64), 0, stream>>>(vals, spart, (float*)d_out, B);
}

// Round 16
// 305.325 us; speedup vs baseline: 1.5835x; 1.5835x over previous
//
#include <hip/hip_runtime.h>

// DILATE loss via the soft-DTW forward/backward identity:
//   E[i,j] = exp((V - R[i,j] - Rrev[i,j] + D[i,j]) / gamma)
// Round 16: r14 (267us pass, best) with the STORE-DATA REGISTER-REUSE HAZARD
// removed: each 64-step window runs as 8 groups of 8; results go to 8
// distinct named float2 regs, stored at group end -> a store's data reg is
// next overwritten 8 steps later, so compiler vmcnt waits are non-blocking
// (VGPR16 reuse previously forced a ~vmcnt(0) store-drain stall EVERY step).
// __launch_bounds__(256,1) uncaps the register allocator.
// Scaled domain R'' = R * (100/ln2).

#define NSEQ 512
#define K2   144.269504088896f      // (1/gamma)*log2(e) = 100/ln2
#define SC   0.006931471805599453f  // ln2/100
#define BIGV 1e10f
#define ALPHA 0.5f
#define PACKS 327680                // floats per sample per dir (4*640*128)

// full-wave shift toward higher lanes by 1 (lane l gets lane l-1); lane 0 -> BIGV
__device__ __forceinline__ float shr1(float v) {
    return __int_as_float(__builtin_amdgcn_update_dpp(
        __float_as_int(BIGV), __float_as_int(v), 0x138 /*wave_shr:1*/,
        0xF, 0xF, false));
}

__global__ __launch_bounds__(256, 1) void sdtw_pass(
    const float* __restrict__ outp, const float* __restrict__ targ,
    float* __restrict__ slabA, float* __restrict__ slabB,
    float* __restrict__ vals, float* __restrict__ vraw, int kbase)
{
    const int tid = threadIdx.x;
    const int w = tid >> 6, l = tid & 63;
    const int i0 = 128 * w + 2 * l;          // lane owns rows i0, i0+1
    const int dir = blockIdx.x & 1;
    const int kk  = blockIdx.x >> 1;
    const int k   = kbase + kk;
    const bool lane0 = (l == 0), lane63 = (l == 63);

    __shared__ float o_pad[644];   // o[j] at [j+1], pads 0
    __shared__ float t_sh[516];
    __shared__ float Rbf[3][644];  // boundary row 128(w+1)-1 by column (col c at [c+1])
    __shared__ float dummyF[644];  // virtual row -1: [0]=0 (R[-1,-1]), else BIG

    for (int q = tid; q < 644; q += 256) { o_pad[q] = 0.f; dummyF[q] = BIGV; }
    for (int q = tid; q < 516; q += 256) t_sh[q] = 0.f;
    __syncthreads();
    if (tid == 0) {
        dummyF[0] = 0.f;                     // virtual R[-1,-1] = 0
        Rbf[0][0] = BIGV; Rbf[1][0] = BIGV; Rbf[2][0] = BIGV;
    }
    for (int q = tid; q < NSEQ; q += 256) {  // dir 1: reversed sequences
        const int src = dir ? (NSEQ - 1 - q) : q;
        o_pad[1 + q] = outp[(size_t)k * NSEQ + src];
        t_sh[q]      = targ[(size_t)k * NSEQ + src];
    }
    __syncthreads();

    const float t0 = t_sh[i0], t1 = t_sh[i0 + 1];
    const float* RbfR = (w == 0) ? dummyF : Rbf[w - 1];
    float*       RbfW = Rbf[w < 3 ? w : 2];          // guarded by (w<3)

    float2* __restrict__ sp2 =
        (float2*)((dir ? slabB : slabA) + (size_t)kk * PACKS) + w * 40960 + l;

    float rp1_0 = BIGV, rp1_1 = BIGV, rp2_0 = BIGV, rp2_1 = BIGV;
    float sbv = BIGV;                        // carried shr1(rp1_1) == previous sA
    float rfinal = BIGV;

    for (int ss = 0; ss < 19; ++ss) {
        const int mw = ss - 3 * w;               // wave-local window
        if (0 <= mw && mw < 10) {
            const int tb = (mw + 2 * w) * 64;    // global diag base
            float2* __restrict__ spw = sp2 + (size_t)(mw * 64) * 64;
            for (int g = 0; g < 8; ++g) {
                float2 stq[8];                   // 8 distinct store-data regs
                #pragma unroll
                for (int q = 0; q < 8; ++q) {
                    const int u = 8 * g + q;
                    const int jj = tb - i0 + u;      // column of cell r=0
                    const int ob = (jj > 0) ? jj : 0;
                    const float oj  = o_pad[ob + 1];     // o[jj]
                    const float ojm = o_pad[ob];         // o[jj-1]
                    const float bdA = RbfR[ob + 1];      // R[i0-1, jj]
                    const float bdB = RbfR[ob];          // R[i0-1, jj-1]
                    const float sA = shr1(rp1_1);        // R[i0-1, jj] via DPP
                    const float sB = sbv;                // carry of prev sA
                    const float a0 = lane0 ? bdA : sA;
                    const float b0 = lane0 ? bdB : sB;
                    const float c0 = rp1_0;
                    // cell r=0: (i0, jj)
                    float mn0 = fminf(fminf(a0, b0), c0);
                    float mx0 = fmaxf(fmaxf(a0, b0), c0);
                    float md0 = __builtin_amdgcn_fmed3f(a0, b0, c0);
                    float s0 = 1.0f + __builtin_exp2f(mn0 - md0) + __builtin_exp2f(mn0 - mx0);
                    float sm0 = mn0 - __builtin_log2f(s0);
                    float dv0 = t0 - oj;
                    float r0v = fmaf(dv0 * dv0, K2, sm0);
                    // cell r=1: (i0+1, jj-1) — pre-rotation registers only
                    float mn1 = fminf(fminf(rp1_0, rp2_0), rp1_1);
                    float mx1 = fmaxf(fmaxf(rp1_0, rp2_0), rp1_1);
                    float md1 = __builtin_amdgcn_fmed3f(rp1_0, rp2_0, rp1_1);
                    float s1 = 1.0f + __builtin_exp2f(mn1 - md1) + __builtin_exp2f(mn1 - mx1);
                    float sm1 = mn1 - __builtin_log2f(s1);
                    float dv1 = t1 - ojm;
                    float r1v = fmaf(dv1 * dv1, K2, sm1);
                    const bool act0 = ((unsigned)jj < 512u);
                    const bool act1 = ((unsigned)(jj - 1) < 512u);
                    const float r0n = act0 ? r0v : BIGV;
                    const float r1n = act1 ? r1v : BIGV;
                    rp2_0 = rp1_0; rp1_0 = r0n;
                    rp2_1 = rp1_1; rp1_1 = r1n;
                    sbv = sA;                            // next step's sB
                    stq[q] = make_float2(r0v, r1v);      // buffered store data
                    if (lane63 && w < 3 && act1) RbfW[jj] = r1n;  // boundary export
                    if (u == 62 && mw == 9) rfinal = r1v;         // cell (511,511)
                }
                #pragma unroll
                for (int q = 0; q < 8; ++q)              // grouped stores:
                    spw[(8 * g + q) * 64] = stq[q];      // regs reused 8 steps later
            }
        }
        asm volatile("s_waitcnt lgkmcnt(0)\n\ts_barrier" ::: "memory");
    }
    if (w == 3 && lane63 && dir == 0) { vals[k] = rfinal * SC; vraw[k] = rfinal; }
}

// ---------------- pointwise E map-reduce ----------------
// E[i,j] = exp2(Vraw - A[i,j] - B[i',j'] + D[i,j]*K2); acc += E*(i-j)^2,
// with (i',j') = (511-i, 511-j) in the reverse pass's skewed layout.
// float offset of cell (i,j): (i>>7)*65536 + (i+j)*128 + (i&127).
__global__ __launch_bounds__(256) void ereduce(
    const float* __restrict__ outp, const float* __restrict__ targ,
    const float* __restrict__ slabA, const float* __restrict__ slabB,
    const float* __restrict__ vraw, float* __restrict__ spart, int kbase)
{
    const int tid = threadIdx.x;
    const int sect = blockIdx.x & 15;
    const int kk = blockIdx.x >> 4;
    const int k = kbase + kk;

    __shared__ float t_sh[NSEQ], o_sh[NSEQ];
    __shared__ float red[4];
    for (int q = tid; q < NSEQ; q += 256) {
        t_sh[q] = targ[(size_t)k * NSEQ + q];
        o_sh[q] = outp[(size_t)k * NSEQ + q];
    }
    __syncthreads();

    const float* __restrict__ A  = slabA + (size_t)kk * PACKS;
    const float* __restrict__ Bs = slabB + (size_t)kk * PACKS;
    const float V = vraw[k];
    float acc = 0.f;
    const int dend = (sect == 15) ? 1023 : (sect * 64 + 64);
    for (int d = sect * 64; d < dend; ++d) {
        const int ilo = (d > 511) ? (d - 511) : 0;
        const int ihi = (d < 512) ? d : 511;
        const int dbA = d * 128;
        const int dbB = (1022 - d) * 128;
        for (int i = ilo + tid; i <= ihi; i += 256) {
            const int i2 = 511 - i;
            const float a = A [((i  >> 7) << 16) + dbA + (i  & 127)];
            const float b = Bs[((i2 >> 7) << 16) + dbB + (i2 & 127)];
            const float dv = t_sh[i] - o_sh[d - i];
            const float arg = fmaf(dv * dv, K2, V - a - b);
            const float E = __builtin_exp2f(arg);       // in [0, 1+eps]
            const float df = (float)(2 * i - d);        // i - j
            acc = fmaf(E * df, df, acc);
        }
    }
    for (int off = 32; off; off >>= 1) acc += __shfl_down(acc, off);
    if ((tid & 63) == 0) red[tid >> 6] = acc;
    __syncthreads();
    if (tid == 0) spart[k * 16 + sect] = red[0] + red[1] + red[2] + red[3];
}

__global__ void finalize_kernel(const float* __restrict__ vals,
                                const float* __restrict__ spart,
                                float* __restrict__ out, int B) {
    int t = threadIdx.x;    // 64 threads
    float v = 0.0f, s = 0.0f;
    for (int q = t; q < B; q += 64) v += vals[q];
    for (int q = t; q < 16 * B; q += 64) s += spart[q];
    for (int off = 32; off; off >>= 1) { v += __shfl_down(v, off); s += __shfl_down(s, off); }
    if (t == 0) {
        float loss_shape = v / (float)B;
        float loss_temporal = (s / (float)B) / ((float)NSEQ * (float)NSEQ);
        out[0] = ALPHA * loss_shape + (1.0f - ALPHA) * loss_temporal;
    }
}

extern "C" void kernel_launch(void* const* d_in, const int* in_sizes, int n_in,
                              void* d_out, int out_size, void* d_ws, size_t ws_size,
                              hipStream_t stream) {
    const float* outputs = (const float*)d_in[0];
    const float* targets = (const float*)d_in[1];
    const int B = in_sizes[0] / NSEQ;    // 64

    // ws: [0,256B) vals, [256,512B) vraw, [512,4608B) spart, [8192, ...) slabs
    float* vals  = (float*)d_ws;
    float* vraw  = vals + 64;
    float* spart = vals + 128;
    float* slabs = (float*)((char*)d_ws + 8192);

    const size_t per_sample = 2 * (size_t)PACKS * sizeof(float);   // 2.5 MiB (A+B)
    size_t avail = (ws_size > 8192) ? (ws_size - 8192) / per_sample : 0;
    int G = (int)((avail < (size_t)B) ? avail : (size_t)B);
    if (G < 1) G = 1;
    float* slabA = slabs;
    float* slabB = slabs + (size_t)G * PACKS;

    for (int kb = 0; kb < B; kb += G) {
        int g = (B - kb < G) ? (B - kb) : G;
        sdtw_pass<<<dim3(2 * g), dim3(256), 0, stream>>>(
            outputs, targets, slabA, slabB, vals, vraw, kb);
        ereduce<<<dim3(16 * g), dim3(256), 0, stream>>>(
            outputs, targets, slabA, slabB, vraw, spart, kb);
    }
    finalize_kernel<<<dim3(1), dim3(64), 0, stream>>>(vals, spart, (float*)d_out, B);
}

// Round 17
// 269.018 us; speedup vs baseline: 1.7972x; 1.1350x over previous
//
#include <hip/hip_runtime.h>

// DILATE loss via the soft-DTW forward/backward identity:
//   E[i,j] = exp((V - R[i,j] - Rrev[i,j] + D[i,j]) / gamma)
// Round 17: r16 (245us pass) + DOUBLE-BUFFERED PER-GROUP LDS PREFETCH:
// each 64-step window = 8 groups of 8; group g+1's o/boundary values are
// batch-loaded into named regs while group g's chain computes (~1000cy cover
// vs ~120cy LDS latency). ojm/bdB become register carries. In-chain per-step
// memory ops: ZERO. Grouped stores kept (r16 win). Scaled domain R''.

#define NSEQ 512
#define K2   144.269504088896f      // (1/gamma)*log2(e) = 100/ln2
#define SC   0.006931471805599453f  // ln2/100
#define BIGV 1e10f
#define ALPHA 0.5f
#define PACKS 327680                // floats per sample per dir (4*640*128)

// full-wave shift toward higher lanes by 1 (lane l gets lane l-1); lane 0 -> BIGV
__device__ __forceinline__ float shr1(float v) {
    return __int_as_float(__builtin_amdgcn_update_dpp(
        __float_as_int(BIGV), __float_as_int(v), 0x138 /*wave_shr:1*/,
        0xF, 0xF, false));
}

__global__ __launch_bounds__(256, 1) void sdtw_pass(
    const float* __restrict__ outp, const float* __restrict__ targ,
    float* __restrict__ slabA, float* __restrict__ slabB,
    float* __restrict__ vals, float* __restrict__ vraw, int kbase)
{
    const int tid = threadIdx.x;
    const int w = tid >> 6, l = tid & 63;
    const int i0 = 128 * w + 2 * l;          // lane owns rows i0, i0+1
    const int dir = blockIdx.x & 1;
    const int kk  = blockIdx.x >> 1;
    const int k   = kbase + kk;
    const bool lane0 = (l == 0), lane63 = (l == 63);

    __shared__ float o_pad[644];   // o[j] at [j+1], pads 0
    __shared__ float t_sh[516];
    __shared__ float Rbf[3][644];  // boundary row 128(w+1)-1 by column (col c at [c+1])
    __shared__ float dummyF[644];  // virtual row -1: [0]=0 (R[-1,-1]), else BIG

    for (int q = tid; q < 644; q += 256) { o_pad[q] = 0.f; dummyF[q] = BIGV; }
    for (int q = tid; q < 516; q += 256) t_sh[q] = 0.f;
    __syncthreads();
    if (tid == 0) {
        dummyF[0] = 0.f;                     // virtual R[-1,-1] = 0
        Rbf[0][0] = BIGV; Rbf[1][0] = BIGV; Rbf[2][0] = BIGV;
    }
    for (int q = tid; q < NSEQ; q += 256) {  // dir 1: reversed sequences
        const int src = dir ? (NSEQ - 1 - q) : q;
        o_pad[1 + q] = outp[(size_t)k * NSEQ + src];
        t_sh[q]      = targ[(size_t)k * NSEQ + src];
    }
    __syncthreads();

    const float t0 = t_sh[i0], t1 = t_sh[i0 + 1];
    const float* RbfR = (w == 0) ? dummyF : Rbf[w - 1];
    float*       RbfW = Rbf[w < 3 ? w : 2];          // guarded by (w<3)

    float2* __restrict__ sp2 =
        (float2*)((dir ? slabB : slabA) + (size_t)kk * PACKS) + w * 40960 + l;

    float rp1_0 = BIGV, rp1_1 = BIGV, rp2_0 = BIGV, rp2_1 = BIGV;
    float sbv = BIGV;                        // carried shr1(rp1_1) == previous sA
    float rfinal = BIGV;

// batched group load: 8 o-values + 8 boundary values into named regs
#define LOADG(OQ, BQ, GB)                                                 \
    _Pragma("unroll") for (int q = 0; q < 8; ++q) {                       \
        const int jj = jw0 + (GB) + q;                                    \
        const int ob = (jj > 0) ? jj : 0;                                 \
        OQ[q] = o_pad[ob + 1];                                            \
        BQ[q] = RbfR[ob + 1];                                             \
    }

// 8-step chain group using prefetched OQ/BQ; carries: ojmc, bdBc, sbv
#define BODYG(OQ, BQ, GB)                                                 \
    _Pragma("unroll") for (int q = 0; q < 8; ++q) {                       \
        const int u = (GB) + q;                                           \
        const int jj = jw0 + u;                                           \
        const float oj  = OQ[q];                                          \
        const float ojm = ojmc;                                           \
        const float bdA = BQ[q];                                          \
        const float bdB = bdBc;                                           \
        const float sA = shr1(rp1_1);                                     \
        const float sB = sbv;                                             \
        const float a0 = lane0 ? bdA : sA;                                \
        const float b0 = lane0 ? bdB : sB;                                \
        const float c0 = rp1_0;                                           \
        float mn0 = fminf(fminf(a0, b0), c0);                             \
        float mx0 = fmaxf(fmaxf(a0, b0), c0);                             \
        float md0 = __builtin_amdgcn_fmed3f(a0, b0, c0);                  \
        float s0 = 1.0f + __builtin_exp2f(mn0 - md0)                      \
                        + __builtin_exp2f(mn0 - mx0);                     \
        float sm0 = mn0 - __builtin_log2f(s0);                            \
        float dv0 = t0 - oj;                                              \
        float r0v = fmaf(dv0 * dv0, K2, sm0);                             \
        float mn1 = fminf(fminf(rp1_0, rp2_0), rp1_1);                    \
        float mx1 = fmaxf(fmaxf(rp1_0, rp2_0), rp1_1);                    \
        float md1 = __builtin_amdgcn_fmed3f(rp1_0, rp2_0, rp1_1);         \
        float s1 = 1.0f + __builtin_exp2f(mn1 - md1)                      \
                        + __builtin_exp2f(mn1 - mx1);                     \
        float sm1 = mn1 - __builtin_log2f(s1);                            \
        float dv1 = t1 - ojm;                                             \
        float r1v = fmaf(dv1 * dv1, K2, sm1);                             \
        const bool act0 = ((unsigned)jj < 512u);                          \
        const bool act1 = ((unsigned)(jj - 1) < 512u);                    \
        const float r0n = act0 ? r0v : BIGV;                              \
        const float r1n = act1 ? r1v : BIGV;                              \
        rp2_0 = rp1_0; rp1_0 = r0n;                                       \
        rp2_1 = rp1_1; rp1_1 = r1n;                                       \
        sbv = sA; ojmc = oj; bdBc = bdA;                                  \
        stq[q] = make_float2(r0v, r1v);                                   \
        if (lane63 && w < 3 && act1) RbfW[jj] = r1n;                      \
        if ((GB) + q == 62 && mw == 9) rfinal = r1v;                      \
    }                                                                     \
    _Pragma("unroll") for (int q = 0; q < 8; ++q)                         \
        spw[((GB) + q) * 64] = stq[q];

    for (int ss = 0; ss < 19; ++ss) {
        const int mw = ss - 3 * w;               // wave-local window
        if (0 <= mw && mw < 10) {
            const int tb = (mw + 2 * w) * 64;    // global diag base
            const int jw0 = tb - i0;             // column of r=0 cell at u=0
            float2* __restrict__ spw = sp2 + (size_t)(mw * 64) * 64;
            // window-start carries (reproduce r16's clamped reads)
            const int ob0 = (jw0 > 0) ? jw0 : 0;
            float ojmc = o_pad[ob0];             // o[jw0-1] (pad 0 / clamp)
            float bdBc = RbfR[ob0];              // R[i0-1, jw0-1] (sentinel/virtual)
            float oqA[8], bqA[8], oqB[8], bqB[8];
            float2 stq[8];
            LOADG(oqA, bqA, 0)
            LOADG(oqB, bqB, 8)  BODYG(oqA, bqA, 0)
            LOADG(oqA, bqA, 16) BODYG(oqB, bqB, 8)
            LOADG(oqB, bqB, 24) BODYG(oqA, bqA, 16)
            LOADG(oqA, bqA, 32) BODYG(oqB, bqB, 24)
            LOADG(oqB, bqB, 40) BODYG(oqA, bqA, 32)
            LOADG(oqA, bqA, 48) BODYG(oqB, bqB, 40)
            LOADG(oqB, bqB, 56) BODYG(oqA, bqA, 48)
            BODYG(oqB, bqB, 56)
        }
        asm volatile("s_waitcnt lgkmcnt(0)\n\ts_barrier" ::: "memory");
    }
    if (w == 3 && lane63 && dir == 0) { vals[k] = rfinal * SC; vraw[k] = rfinal; }
#undef LOADG
#undef BODYG
}

// ---------------- pointwise E map-reduce ----------------
// E[i,j] = exp2(Vraw - A[i,j] - B[i',j'] + D[i,j]*K2); acc += E*(i-j)^2,
// with (i',j') = (511-i, 511-j) in the reverse pass's skewed layout.
// float offset of cell (i,j): (i>>7)*65536 + (i+j)*128 + (i&127).
__global__ __launch_bounds__(256) void ereduce(
    const float* __restrict__ outp, const float* __restrict__ targ,
    const float* __restrict__ slabA, const float* __restrict__ slabB,
    const float* __restrict__ vraw, float* __restrict__ spart, int kbase)
{
    const int tid = threadIdx.x;
    const int sect = blockIdx.x & 15;
    const int kk = blockIdx.x >> 4;
    const int k = kbase + kk;

    __shared__ float t_sh[NSEQ], o_sh[NSEQ];
    __shared__ float red[4];
    for (int q = tid; q < NSEQ; q += 256) {
        t_sh[q] = targ[(size_t)k * NSEQ + q];
        o_sh[q] = outp[(size_t)k * NSEQ + q];
    }
    __syncthreads();

    const float* __restrict__ A  = slabA + (size_t)kk * PACKS;
    const float* __restrict__ Bs = slabB + (size_t)kk * PACKS;
    const float V = vraw[k];
    float acc = 0.f;
    const int dend = (sect == 15) ? 1023 : (sect * 64 + 64);
    for (int d = sect * 64; d < dend; ++d) {
        const int ilo = (d > 511) ? (d - 511) : 0;
        const int ihi = (d < 512) ? d : 511;
        const int dbA = d * 128;
        const int dbB = (1022 - d) * 128;
        for (int i = ilo + tid; i <= ihi; i += 256) {
            const int i2 = 511 - i;
            const float a = A [((i  >> 7) << 16) + dbA + (i  & 127)];
            const float b = Bs[((i2 >> 7) << 16) + dbB + (i2 & 127)];
            const float dv = t_sh[i] - o_sh[d - i];
            const float arg = fmaf(dv * dv, K2, V - a - b);
            const float E = __builtin_exp2f(arg);       // in [0, 1+eps]
            const float df = (float)(2 * i - d);        // i - j
            acc = fmaf(E * df, df, acc);
        }
    }
    for (int off = 32; off; off >>= 1) acc += __shfl_down(acc, off);
    if ((tid & 63) == 0) red[tid >> 6] = acc;
    __syncthreads();
    if (tid == 0) spart[k * 16 + sect] = red[0] + red[1] + red[2] + red[3];
}

__global__ void finalize_kernel(const float* __restrict__ vals,
                                const float* __restrict__ spart,
                                float* __restrict__ out, int B) {
    int t = threadIdx.x;    // 64 threads
    float v = 0.0f, s = 0.0f;
    for (int q = t; q < B; q += 64) v += vals[q];
    for (int q = t; q < 16 * B; q += 64) s += spart[q];
    for (int off = 32; off; off >>= 1) { v += __shfl_down(v, off); s += __shfl_down(s, off); }
    if (t == 0) {
        float loss_shape = v / (float)B;
        float loss_temporal = (s / (float)B) / ((float)NSEQ * (float)NSEQ);
        out[0] = ALPHA * loss_shape + (1.0f - ALPHA) * loss_temporal;
    }
}

extern "C" void kernel_launch(void* const* d_in, const int* in_sizes, int n_in,
                              void* d_out, int out_size, void* d_ws, size_t ws_size,
                              hipStream_t stream) {
    const float* outputs = (const float*)d_in[0];
    const float* targets = (const float*)d_in[1];
    const int B = in_sizes[0] / NSEQ;    // 64

    // ws: [0,256B) vals, [256,512B) vraw, [512,4608B) spart, [8192, ...) slabs
    float* vals  = (float*)d_ws;
    float* vraw  = vals + 64;
    float* spart = vals + 128;
    float* slabs = (float*)((char*)d_ws + 8192);

    const size_t per_sample = 2 * (size_t)PACKS * sizeof(float);   // 2.5 MiB (A+B)
    size_t avail = (ws_size > 8192) ? (ws_size - 8192) / per_sample : 0;
    int G = (int)((avail < (size_t)B) ? avail : (size_t)B);
    if (G < 1) G = 1;
    float* slabA = slabs;
    float* slabB = slabs + (size_t)G * PACKS;

    for (int kb = 0; kb < B; kb += G) {
        int g = (B - kb < G) ? (B - kb) : G;
        sdtw_pass<<<dim3(2 * g), dim3(256), 0, stream>>>(
            outputs, targets, slabA, slabB, vals, vraw, kb);
        ereduce<<<dim3(16 * g), dim3(256), 0, stream>>>(
            outputs, targets, slabA, slabB, vraw, spart, kb);
    }
    finalize_kernel<<<dim3(1), dim3(64), 0, stream>>>(vals, spart, (float*)d_out, B);
}